// Round 1
// baseline (478.279 us; speedup 1.0000x reference)
//
#include <hip/hip_runtime.h>
#include <stdint.h>

#define NVOX 400000
#define KTAPS 27
#define TILE 128
#define CAP 1024
#define NCHUNK_CAP (CAP / 16 + KTAPS)   // 91

typedef __bf16 bf16x8 __attribute__((ext_vector_type(8)));
typedef float floatx4 __attribute__((ext_vector_type(4)));

__device__ __forceinline__ uint32_t f2bf(float f) {
  uint32_t u = __builtin_bit_cast(uint32_t, f);
  u += 0x7fffu + ((u >> 16) & 1u);
  return u >> 16;
}

// Weight convert + transpose: Wt[k][co][ci] = bf16(W[k][ci][co]). 432 blocks.
__global__ void k_wt(const float* __restrict__ W, unsigned short* __restrict__ Wt) {
  int i = blockIdx.x * 256 + threadIdx.x;
  int k = i >> 12;
  int rem = i & 4095;
  int ci = rem >> 6;
  int co = rem & 63;
  Wt[(k << 12) + (co << 6) + ci] = (unsigned short)f2bf(W[i]);
}

// Sparse gather-GEMM conv. Block = 128 output voxels, 256 threads (4 waves).
// Grid sparsity is 5.66% -> off-center taps have ~7 valid rows per 128-tile.
// Compact valid (row, idx) pairs per tap in-block, run 16-row MFMA chunks,
// scatter-add into per-wave LDS accumulator slabs (no atomics, no races).
__global__ __launch_bounds__(256, 3) void k_conv(
    const float* __restrict__ feats,
    const unsigned short* __restrict__ Wt,     // [k][co][ci] bf16
    const float* __restrict__ bias,
    const int* __restrict__ nbr,               // [27][NVOX]
    float* __restrict__ out) {                 // [NVOX][64]

  __shared__ float accS[4 * TILE * 16];                  // 32768 B: wave w owns couts [16w,16w+16)
  __shared__ alignas(16) unsigned short lA[2][16 * 72];  // 4608 B: dbuf A chunk, pitch 72 (bank-safe)
  __shared__ int pairIdx[CAP];                           // 4096 B
  __shared__ unsigned short pairRow[CAP];                // 2048 B
  __shared__ unsigned long long masksS[KTAPS * 2];       // 432 B
  __shared__ int woff[KTAPS * 2 + 1];                    // 220 B
  __shared__ unsigned int chunkTab[NCHUNK_CAP];          // 364 B: k<<16 | start<<5 | len
  __shared__ int nChunksS;

  const int t = threadIdx.x;
  const int w = t >> 6;
  const int l = t & 63;

  // Bijective chunked XCD swizzle (m204): consecutive work -> same XCD L2.
  const int nwg = gridDim.x;
  const int q = nwg >> 3, r8 = nwg & 7;
  const int xcd = blockIdx.x & 7, hi = blockIdx.x >> 3;
  const int wg = (xcd < r8 ? xcd * (q + 1) : r8 * (q + 1) + (xcd - r8) * q) + hi;
  const int v0 = wg * TILE;

  // zero accumulator slabs
  {
    float4 z = make_float4(0.f, 0.f, 0.f, 0.f);
    float4* a4 = (float4*)accS;
#pragma unroll
    for (int i = 0; i < 8; ++i) a4[t + i * 256] = z;
  }

  // ---- compaction pass 1: ballot masks per (tap, wave) ----
#pragma unroll
  for (int k = 0; k < KTAPS; ++k) {
    int id = (t < TILE) ? nbr[(size_t)k * NVOX + v0 + t] : -1;
    unsigned long long m = __ballot(id >= 0);
    if (l == 0 && w < 2) masksS[k * 2 + w] = m;
  }
  __syncthreads();
  // exclusive prefix over the 54 (tap,wave) counts -> pair offsets (wave 0)
  if (w == 0) {
    int c = (l < KTAPS * 2) ? __popcll(masksS[l]) : 0;
#pragma unroll
    for (int d = 1; d < 64; d <<= 1) { int o = __shfl_up(c, d); if (l >= d) c += o; }
    if (l < KTAPS * 2) woff[l + 1] = c;
    if (l == 0) woff[0] = 0;
  }
  __syncthreads();
  // ---- compaction pass 2: write (row, idx) pairs grouped by tap ----
#pragma unroll
  for (int k = 0; k < KTAPS; ++k) {
    int id = (t < TILE) ? nbr[(size_t)k * NVOX + v0 + t] : -1;
    if (id >= 0) {
      unsigned long long m = masksS[k * 2 + w];
      int pos = woff[k * 2 + w] + __popcll(m & ((1ull << l) - 1ull));
      if (pos < CAP) { pairRow[pos] = (unsigned short)t; pairIdx[pos] = id; }
    }
  }
  // chunk table: tap k -> ceil(cnt/16) chunks of <=16 rows (wave 0)
  if (w == 0) {
    int b0 = 0, cnt = 0;
    if (l < KTAPS) {
      b0 = min(woff[2 * l], CAP);
      cnt = min(woff[2 * l + 2], CAP) - b0;
    }
    int nch = (cnt + 15) >> 4;
    int inc = nch;
#pragma unroll
    for (int d = 1; d < 64; d <<= 1) { int o = __shfl_up(inc, d); if (l >= d) inc += o; }
    int base = inc - nch;
    for (int j = 0; j < nch; ++j) {
      int st = b0 + 16 * j;
      int ln = min(16, cnt - 16 * j);
      chunkTab[base + j] = ((unsigned)l << 16) | ((unsigned)st << 5) | (unsigned)ln;
    }
    if (l == KTAPS - 1) nChunksS = inc;
  }
  __syncthreads();
  const int nc = nChunksS;

  const int rr = t >> 3;   // staging row 0..15 (threads 0..127)
  const int jc = t & 7;    // 16B (8-channel) slice within the row

  // gather one chunk's A rows into registers (fp32 -> bf16 on the fly)
  auto gatherA = [&](unsigned int meta, uint4& sreg, bool& svalid) {
    int st = (meta >> 5) & 0x7FF;
    int ln = (int)(meta & 31u);
    svalid = (t < TILE) && (rr < ln);
    if (svalid) {
      int idx = pairIdx[st + rr];
      const float* s = feats + (size_t)idx * 64 + jc * 8;
      float4 f0 = *(const float4*)s;
      float4 f1 = *(const float4*)(s + 4);
      uint4 d;
      d.x = f2bf(f0.x) | (f2bf(f0.y) << 16);
      d.y = f2bf(f0.z) | (f2bf(f0.w) << 16);
      d.z = f2bf(f1.x) | (f2bf(f1.y) << 16);
      d.w = f2bf(f1.z) | (f2bf(f1.w) << 16);
      sreg = d;
    }
  };
  // B frag for this wave's 16-cout slice of W[k]: lane l -> co = w*16 + (l&15), ci = (l>>4)*8 (+32)
  auto bload = [&](int k, uint4& b0, uint4& b1) {
    const unsigned short* src = Wt + (k << 12) + (w * 16 + (l & 15)) * 64 + ((l >> 4) * 8);
    b0 = *(const uint4*)src;
    b1 = *(const uint4*)(src + 32);
  };

  unsigned int mCur = 0, mNxt = 0;
  uint4 sA0, sA1;
  bool sV0 = false, sV1 = false;
  uint4 rB0, rB1;

  if (nc > 0) {
    mCur = chunkTab[0];
    gatherA(mCur, sA0, sV0);
    bload((int)(mCur >> 16), rB0, rB1);
  }
  if (nc > 1) {
    mNxt = chunkTab[1];
    gatherA(mNxt, sA1, sV1);
  }

#pragma unroll 1
  for (int c = 0; c < nc; ++c) {
    __syncthreads();   // buf (c&1) no longer being read (chunk c-2 done by all)
    {
      bool sv = (c & 1) ? sV1 : sV0;
      uint4 v = (c & 1) ? sA1 : sA0;
      if (sv) *(uint4*)&lA[c & 1][rr * 72 + jc * 8] = v;  // rows >= len keep stale data; never scattered
    }
    __syncthreads();   // chunk c's A tile ready

    const int kCur = (int)(mCur >> 16);
    const int stCur = (int)((mCur >> 5) & 0x7FF);
    const int lnCur = (int)(mCur & 31u);

    // prefetch gather for chunk c+2 into the sA slot just flushed (2-deep pipeline)
    unsigned int mNew = 0;
    if (c + 2 < nc) {
      mNew = chunkTab[c + 2];
      if ((c & 1) == 0) gatherA(mNew, sA0, sV0);
      else              gatherA(mNew, sA1, sV1);
    } else {
      if ((c & 1) == 0) sV0 = false; else sV1 = false;
    }
    // prefetch B for chunk c+1 (skip reload when same tap, e.g. center-tap runs)
    uint4 nB0 = rB0, nB1 = rB1;
    if (c + 1 < nc) {
      int kN = (int)(mNxt >> 16);
      if (kN != kCur) bload(kN, nB0, nB1);
    }

    // MFMA: [16 rows x 64 ci] @ [64 ci x 16 couts] for this wave's slice
    const unsigned short* aB = &lA[c & 1][(l & 15) * 72 + ((l >> 4) * 8)];
    bf16x8 a0 = *(const bf16x8*)aB;
    bf16x8 a1 = *(const bf16x8*)(aB + 32);
    floatx4 d = {0.f, 0.f, 0.f, 0.f};
    d = __builtin_amdgcn_mfma_f32_16x16x32_bf16(a0, __builtin_bit_cast(bf16x8, rB0), d, 0, 0, 0);
    d = __builtin_amdgcn_mfma_f32_16x16x32_bf16(a1, __builtin_bit_cast(bf16x8, rB1), d, 0, 0, 0);

    // scatter-add: D col = lane&15 (cout), row = (lane>>4)*4 + reg (m89 layout).
    // (tr, col) unique within wave; waves own disjoint cout slabs -> plain RMW.
    float* slab = accS + w * (TILE * 16) + (l & 15);
#pragma unroll
    for (int j2 = 0; j2 < 4; ++j2) {
      int r2 = (l >> 4) * 4 + j2;
      if (r2 < lnCur) {
        int tr = pairRow[stCur + r2];
        slab[tr * 16] += d[j2];
      }
    }

    mCur = mNxt; mNxt = mNew; rB0 = nB0; rB1 = nB1;
  }

  // ---- epilogue: out = acc + bias (coalesced float4) ----
  __syncthreads();
  {
    int vox = t >> 1;
    int cb = (t & 1) * 32;
    float* op = out + (size_t)(v0 + vox) * 64 + cb;
#pragma unroll
    for (int qq = 0; qq < 8; ++qq) {
      int c0 = cb + qq * 4;
      const float* ap = accS + (c0 >> 4) * (TILE * 16) + vox * 16 + (c0 & 15);
      float4 v = *(const float4*)ap;
      float4 bv = *(const float4*)(bias + c0);
      v.x += bv.x; v.y += bv.y; v.z += bv.z; v.w += bv.w;
      *(float4*)(op + qq * 4) = v;
    }
  }
}

extern "C" void kernel_launch(void* const* d_in, const int* in_sizes, int n_in,
                              void* d_out, int out_size, void* d_ws, size_t ws_size,
                              hipStream_t stream) {
  const float* feats  = (const float*)d_in[0];
  const float* weight = (const float*)d_in[1];
  const float* bias   = (const float*)d_in[2];
  const int*   nbr    = (const int*)d_in[3];
  float* out = (float*)d_out;

  unsigned short* Wt = (unsigned short*)d_ws;   // 27*4096*2 = 221184 B

  k_wt<<<432, 256, 0, stream>>>(weight, Wt);
  k_conv<<<NVOX / TILE, 256, 0, stream>>>(feats, Wt, bias, nbr, out);
}